// Round 1
// baseline (1621.710 us; speedup 1.0000x reference)
//
#include <hip/hip_runtime.h>
#include <hip/hip_bf16.h>

// 5-LOD dense-grid trilinear interpolation.
// pts: [N,3] fp32 in [0,1); cbL: [res^3, 8] fp32; out: [N,8] fp32 = sum over LODs.
// Reference semantics:
//   x  = p * (res-1)
//   x0 = clip(floor(x), 0, res-2)   (int)
//   f  = x - x0
//   idx(corner ijk) = (x0+i) + (y0+j)*res + (z0+k)*res^2
//   w  = (i?fx:1-fx)*(j?fy:1-fy)*(k?fz:1-fz)
//   out += sum_c w_c * cb[idx_c, :]

#define FEAT 8

__global__ __launch_bounds__(256) void dense_grid_kernel(
    const float* __restrict__ pts,
    const float* __restrict__ cb0,
    const float* __restrict__ cb1,
    const float* __restrict__ cb2,
    const float* __restrict__ cb3,
    const float* __restrict__ cb4,
    float* __restrict__ out,
    int n)
{
    int i = blockIdx.x * blockDim.x + threadIdx.x;
    if (i >= n) return;

    const float px = pts[3 * i + 0];
    const float py = pts[3 * i + 1];
    const float pz = pts[3 * i + 2];

    float4 acc_lo = make_float4(0.f, 0.f, 0.f, 0.f);
    float4 acc_hi = make_float4(0.f, 0.f, 0.f, 0.f);

    const float* cbs[5] = {cb0, cb1, cb2, cb3, cb4};
    const int ress[5] = {16, 32, 64, 128, 256};

    #pragma unroll
    for (int L = 0; L < 5; ++L) {
        const int res = ress[L];
        const float* __restrict__ cb = cbs[L];

        const float sx = px * (float)(res - 1);
        const float sy = py * (float)(res - 1);
        const float sz = pz * (float)(res - 1);

        // clip(floor(x), 0, res-2)
        int x0 = (int)floorf(sx); x0 = min(max(x0, 0), res - 2);
        int y0 = (int)floorf(sy); y0 = min(max(y0, 0), res - 2);
        int z0 = (int)floorf(sz); z0 = min(max(z0, 0), res - 2);

        const float fx = sx - (float)x0;
        const float fy = sy - (float)y0;
        const float fz = sz - (float)z0;
        const float gx = 1.f - fx;
        const float gy = 1.f - fy;
        const float gz = 1.f - fz;

        const int base = x0 + y0 * res + z0 * res * res;

        // corner c = i*4 + j*2 + k  (i->x, j->y, k->z)
        const float wgt[8] = {
            gx * gy * gz,  // 000
            gx * gy * fz,  // 001
            gx * fy * gz,  // 010
            gx * fy * fz,  // 011
            fx * gy * gz,  // 100
            fx * gy * fz,  // 101
            fx * fy * gz,  // 110
            fx * fy * fz   // 111
        };
        const int offs[8] = {
            0,
            res * res,
            res,
            res + res * res,
            1,
            1 + res * res,
            1 + res,
            1 + res + res * res
        };

        const float4* __restrict__ cb4p = (const float4*)cb;
        #pragma unroll
        for (int c = 0; c < 8; ++c) {
            const float w = wgt[c];
            const long long row = (long long)(base + offs[c]) * 2;  // 2 float4 per row
            const float4 lo = cb4p[row + 0];
            const float4 hi = cb4p[row + 1];
            acc_lo.x += w * lo.x; acc_lo.y += w * lo.y;
            acc_lo.z += w * lo.z; acc_lo.w += w * lo.w;
            acc_hi.x += w * hi.x; acc_hi.y += w * hi.y;
            acc_hi.z += w * hi.z; acc_hi.w += w * hi.w;
        }
    }

    float4* o = (float4*)(out + (long long)i * FEAT);
    o[0] = acc_lo;
    o[1] = acc_hi;
}

extern "C" void kernel_launch(void* const* d_in, const int* in_sizes, int n_in,
                              void* d_out, int out_size, void* d_ws, size_t ws_size,
                              hipStream_t stream) {
    const float* pts = (const float*)d_in[0];
    const float* cb0 = (const float*)d_in[1];
    const float* cb1 = (const float*)d_in[2];
    const float* cb2 = (const float*)d_in[3];
    const float* cb3 = (const float*)d_in[4];
    const float* cb4 = (const float*)d_in[5];
    float* out = (float*)d_out;

    const int n = in_sizes[0] / 3;
    const int block = 256;
    const int grid = (n + block - 1) / block;
    dense_grid_kernel<<<grid, block, 0, stream>>>(pts, cb0, cb1, cb2, cb3, cb4, out, n);
}

// Round 2
// 1158.032 us; speedup vs baseline: 1.4004x; 1.4004x over previous
//
#include <hip/hip_runtime.h>
#include <hip/hip_bf16.h>

// 5-LOD dense-grid trilinear interpolation, 8 lanes per point (1 lane per corner).
// pts: [N,3] fp32 in [0,1); cbL: [res^3, 8] fp32; out: [N,8] fp32 = sum over LODs.
//
// Lane mapping within a group of 8: c bit0 = x-offset (i), bit1 = y (j), bit2 = z (k)
// so lanes (2m, 2m+1) read x-adjacent rows -> 64 B contiguous, wave-coalesced.
// Each lane accumulates w_c * cb[idx_c, 0:8] over the 5 LODs, then a 3-stage
// shuffle transpose-reduce leaves output element c on lane c (coalesced stores).

#define FEAT 8

__global__ __launch_bounds__(256) void dense_grid_kernel(
    const float* __restrict__ pts,
    const float* __restrict__ cb0,
    const float* __restrict__ cb1,
    const float* __restrict__ cb2,
    const float* __restrict__ cb3,
    const float* __restrict__ cb4,
    float* __restrict__ out,
    int n)
{
    const int t = blockIdx.x * blockDim.x + threadIdx.x;
    const int pi = t >> 3;       // point index
    const int c  = t & 7;        // corner id
    if (pi >= n) return;

    const int ci = c & 1;         // x offset
    const int cj = (c >> 1) & 1;  // y offset
    const int ck = (c >> 2) & 1;  // z offset

    const float px = pts[3 * pi + 0];
    const float py = pts[3 * pi + 1];
    const float pz = pts[3 * pi + 2];

    const float* cbs[5] = {cb0, cb1, cb2, cb3, cb4};
    const int ress[5] = {16, 32, 64, 128, 256};

    float a[8] = {0.f, 0.f, 0.f, 0.f, 0.f, 0.f, 0.f, 0.f};

    #pragma unroll
    for (int L = 0; L < 5; ++L) {
        const int res = ress[L];
        const float* __restrict__ cb = cbs[L];

        const float sx = px * (float)(res - 1);
        const float sy = py * (float)(res - 1);
        const float sz = pz * (float)(res - 1);

        int x0 = (int)floorf(sx); x0 = min(max(x0, 0), res - 2);
        int y0 = (int)floorf(sy); y0 = min(max(y0, 0), res - 2);
        int z0 = (int)floorf(sz); z0 = min(max(z0, 0), res - 2);

        const float fx = sx - (float)x0;
        const float fy = sy - (float)y0;
        const float fz = sz - (float)z0;

        const float w = (ci ? fx : 1.f - fx) *
                        (cj ? fy : 1.f - fy) *
                        (ck ? fz : 1.f - fz);

        const long long row = (long long)((x0 + ci) + (y0 + cj) * res + (z0 + ck) * res * res);
        const float4* __restrict__ p = (const float4*)cb + row * 2;
        const float4 lo = p[0];
        const float4 hi = p[1];

        a[0] += w * lo.x; a[1] += w * lo.y; a[2] += w * lo.z; a[3] += w * lo.w;
        a[4] += w * hi.x; a[5] += w * hi.y; a[6] += w * hi.z; a[7] += w * hi.w;
    }

    // Transpose-reduce across the 8 lanes of this point's group.
    // Stage xor 4: keep/receive the half selected by lane bit2.
    {
        const bool hi4 = (c & 4) != 0;
        #pragma unroll
        for (int f = 0; f < 4; ++f) {
            const float send = hi4 ? a[f] : a[f + 4];
            const float recv = __shfl_xor(send, 4);
            a[f] = (hi4 ? a[f + 4] : a[f]) + recv;
        }
    }
    // Stage xor 2
    {
        const bool hi2 = (c & 2) != 0;
        #pragma unroll
        for (int f = 0; f < 2; ++f) {
            const float send = hi2 ? a[f] : a[f + 2];
            const float recv = __shfl_xor(send, 2);
            a[f] = (hi2 ? a[f + 2] : a[f]) + recv;
        }
    }
    // Stage xor 1
    {
        const bool hi1 = (c & 1) != 0;
        const float send = hi1 ? a[0] : a[1];
        const float recv = __shfl_xor(send, 1);
        const float result = (hi1 ? a[1] : a[0]) + recv;
        // lane c holds output element c
        out[(long long)pi * FEAT + c] = result;
    }
}

extern "C" void kernel_launch(void* const* d_in, const int* in_sizes, int n_in,
                              void* d_out, int out_size, void* d_ws, size_t ws_size,
                              hipStream_t stream) {
    const float* pts = (const float*)d_in[0];
    const float* cb0 = (const float*)d_in[1];
    const float* cb1 = (const float*)d_in[2];
    const float* cb2 = (const float*)d_in[3];
    const float* cb3 = (const float*)d_in[4];
    const float* cb4 = (const float*)d_in[5];
    float* out = (float*)d_out;

    const int n = in_sizes[0] / 3;
    const long long threads = (long long)n * 8;
    const int block = 256;
    const long long grid = (threads + block - 1) / block;
    dense_grid_kernel<<<(int)grid, block, 0, stream>>>(pts, cb0, cb1, cb2, cb3, cb4, out, n);
}